// Round 12
// baseline (59.094 us; speedup 1.0000x reference)
//
#include <hip/hip_runtime.h>

#define LOG2E 1.4426950408889634f

constexpr int D     = 2048;
constexpr int NB    = 16;       // train buffer rows (= MFMA N)
constexpr int TPB   = 512;      // 8 k-waves over an 8-row tile
constexpr int NROWS = 16384;    // B*T
constexpr int RPB   = 8;        // rows per block (A rows 8-15 duplicate 0-7)
constexpr int NBLK  = NROWS / RPB;   // 2048 blocks -> 4 resident/CU
constexpr int NKT   = 8;        // 16x16x32 k-tiles per wave (8*32 = 256 cols)

typedef short bf16x8 __attribute__((ext_vector_type(8)));
typedef float f32x4  __attribute__((ext_vector_type(4)));

__device__ __forceinline__ float gelu_tanh_f(float x) {
    const float C = 0.7978845608028654f;   // sqrt(2/pi)
    const float K = 0.044715f;
    float x2 = x * x;
    float p  = __builtin_fmaf(K, x2, 1.0f);
    float z  = C * x * p;                   // c*(x + K x^3)
    float e  = __builtin_amdgcn_exp2f(z * (2.0f * LOG2E));
    float th = 1.0f - 2.0f * __builtin_amdgcn_rcpf(e + 1.0f);
    float hx = 0.5f * x;
    return __builtin_fmaf(hx, th, hx);      // 0.5x(1+tanh)
}

// round-to-nearest-even f32->bf16, packed pair (a=low16, b=high16)
__device__ __forceinline__ unsigned bpack(float a, float b) {
    unsigned ua = __builtin_bit_cast(unsigned, a);
    unsigned ub = __builtin_bit_cast(unsigned, b);
    ua += 0x7FFFu + ((ua >> 16) & 1u);
    ub += 0x7FFFu + ((ub >> 16) & 1u);
    return (ua >> 16) | (ub & 0xFFFF0000u);
}
__device__ __forceinline__ float blo(unsigned w) {
    return __builtin_bit_cast(float, w << 16);
}
__device__ __forceinline__ float bhi(unsigned w) {
    return __builtin_bit_cast(float, w & 0xFFFF0000u);
}

// ---- pre-pass: buf (16x2048 f32) -> bf16 MFMA B-fragment image in d_ws ----
// dword id -> element n = (id>>2)&15, k = (id>>8)*32 + ((id>>6)&3)*8 + (id&3)*2
// (mapping empirically verified in R7-R11)
__global__ void __launch_bounds__(512) bfrag_kernel(
    const float* __restrict__ buf, unsigned* __restrict__ bfrag)
{
    const int id = blockIdx.x * 512 + threadIdx.x;
    const int n  = (id >> 2) & 15;
    const int k  = ((id >> 8) << 5) + (((id >> 6) & 3) << 3) + ((id & 3) << 1);
    const float* p = buf + n * D + k;
    bfrag[id] = bpack(p[0], p[1]);
}

__global__ void __launch_bounds__(TPB) gelu_gate_kernel(
    const float* __restrict__ x,
    const unsigned* __restrict__ bfrag,   // 16384 dwords, L2-resident
    const int* __restrict__ mask_i,
    const unsigned char* __restrict__ mask_b,
    const float* __restrict__ p_log_tau,
    const float* __restrict__ p_log_blend,
    float* __restrict__ out)
{
    // y-tile: 8 rows x 2048 cols bf16 = 32 KiB, XOR-swizzled (byte ^ (row&7)<<4)
    // so A-fragment ds_read_b128 (16 lanes, 4 KiB row stride) is conflict-light.
    // Total LDS ~37 KiB -> 4 blocks/CU (R11's 73 KiB gave only 2 -> 33% occ).
    __shared__ unsigned ldsY[RPB * D / 2];   // 32 KiB
    __shared__ f32x4    ldsAcc[8][32];       // 4 KiB   (C rows 0-7 only)
    __shared__ float    ldsS2[8][8];         // 256 B
    __shared__ float    ldsGate[8];

    const int t    = threadIdx.x;
    const int lane = t & 63;
    const int wk   = t >> 6;             // k-chunk 0..7

    const float tau   = __builtin_amdgcn_exp2f(p_log_tau[0] * LOG2E);
    const float lbt   = p_log_blend[0];
    const float alpha = __builtin_amdgcn_rcpf(1.0f + __builtin_amdgcn_exp2f(-lbt * LOG2E));

    // bool dtype layout ambiguous (u8 vs i32) -> accept either (all-true dataset)
    unsigned mbits = 0;
#pragma unroll
    for (int k = 0; k < NB; ++k) {
        bool mk = (mask_i[k] != 0) || (mask_b[k] != 0);
        mbits |= (mk ? 1u : 0u) << k;
    }

    const int row0 = blockIdx.x * RPB;
    const float4* x4   = reinterpret_cast<const float4*>(x);
    float4*       out4 = reinterpret_cast<float4*>(out);
    char* ldsYb = reinterpret_cast<char*>(ldsY);

    // ---- phase 1: coalesced x load (all 8 in flight) -> gelu -> bf16 LDS ----
    float4 v[RPB];
#pragma unroll
    for (int j = 0; j < RPB; ++j)
        v[j] = x4[(size_t)(row0 + j) * (D / 4) + t];
#pragma unroll
    for (int j = 0; j < RPB; ++j) {
        uint2 w;
        w.x = bpack(gelu_tanh_f(v[j].x), gelu_tanh_f(v[j].y));
        w.y = bpack(gelu_tanh_f(v[j].z), gelu_tanh_f(v[j].w));
        const int byte = (j * 4096 + 8 * t) ^ (j << 4);
        *reinterpret_cast<uint2*>(ldsYb + byte) = w;
    }
    __syncthreads();

    // ---- phase 2: per-wave MFMA over this wave's 256-col k-chunk ----
    const int m    = lane & 15;          // C col n / A row (rows 8-15 dup 0-7)
    const int mr   = m & 7;              // real x-row
    const int kgrp = lane >> 4;          // 0..3
    const int swzM = mr << 4;
    const char* aBase = ldsYb + mr * 4096;
    const int colB0   = wk * 512 + kgrp * 16;      // byte offset of col window
    const unsigned* Bb = bfrag + wk * (NKT * 256) + lane * 4;

    f32x4 acc = {0.f, 0.f, 0.f, 0.f};
    float s2 = 0.f;
#pragma unroll
    for (int kt = 0; kt < NKT; ++kt) {
        const uint4 af = *reinterpret_cast<const uint4*>(
            aBase + ((colB0 + kt * 64) ^ swzM));
        const uint4 bq = *reinterpret_cast<const uint4*>(Bb + kt * 256);
        acc = __builtin_amdgcn_mfma_f32_16x16x32_bf16(
            __builtin_bit_cast(bf16x8, af), __builtin_bit_cast(bf16x8, bq),
            acc, 0, 0, 0);
        const unsigned ws[4] = { af.x, af.y, af.z, af.w };
#pragma unroll
        for (int c = 0; c < 4; ++c) {
            const float lo = blo(ws[c]), hi = bhi(ws[c]);
            s2 = __builtin_fmaf(lo, lo, s2);
            s2 = __builtin_fmaf(hi, hi, s2);
        }
    }
    // sum the 4 k-groups -> lane holds its chunk's s2 of row mr
    s2 += __shfl_xor(s2, 16, 64);
    s2 += __shfl_xor(s2, 32, 64);

    if (lane < 32) ldsAcc[wk][lane] = acc;   // C rows 0-7 (kgrp 0,1)
    if (lane < 8)  ldsS2[wk][lane] = s2;
    __syncthreads();

    // ---- phase 3: combine across the 8 k-waves ----
    // lanes kgrp 2,3 mirror kgrp 0,1 (duplicate gates, unused rows) -> all defined
    f32x4 dt = ldsAcc[0][lane & 31];
#pragma unroll
    for (int w = 1; w < 8; ++w) dt += ldsAcc[w][lane & 31];

    float gate[4];
#pragma unroll
    for (int j = 0; j < 4; ++j) {
        const int r = (kgrp & 1) * 4 + j;    // real C/x row 0..7
        float s2t = ldsS2[0][r];
#pragma unroll
        for (int w = 1; w < 8; ++w) s2t += ldsS2[w][r];
        const float inv = __builtin_amdgcn_rcpf(fmaxf(__builtin_sqrtf(s2t), 1e-12f));
        float s = dt[j] * inv;               // sim of row r with buf n = m
        if (!((mbits >> m) & 1u)) s = -1.0f;
        s = fmaxf(s, __shfl_xor(s, 1, 64));  // max over n (lane bits 0-3)
        s = fmaxf(s, __shfl_xor(s, 2, 64));
        s = fmaxf(s, __shfl_xor(s, 4, 64));
        s = fmaxf(s, __shfl_xor(s, 8, 64));
        gate[j] = __builtin_fmaf(alpha, __builtin_amdgcn_exp2f(-tau * s * LOG2E),
                                 1.0f - alpha);
    }
    // gate of row q held as reg q&3 at lanes with (kgrp&1) = q>>2
    const int src = ((lane >> 2) & 1) << 4;  // lane holding this lane's row m&7
    const float g0 = __shfl(gate[0], src, 64);
    const float g1 = __shfl(gate[1], src, 64);
    const float g2 = __shfl(gate[2], src, 64);
    const float g3 = __shfl(gate[3], src, 64);
    const float gm = (lane & 2) ? ((lane & 1) ? g3 : g2)
                                : ((lane & 1) ? g1 : g0);
    if (t < 8) ldsGate[t] = gm;   // wave 0 lane q -> gate of row q
    __syncthreads();

    // ---- phase 4: read y back from LDS, scale, coalesced f32 store ----
#pragma unroll
    for (int j = 0; j < RPB; ++j) {
        const int byte = (j * 4096 + 8 * t) ^ (j << 4);
        const uint2 w = *reinterpret_cast<const uint2*>(ldsYb + byte);
        const float gj = ldsGate[j];
        float4 o;
        o.x = blo(w.x) * gj; o.y = bhi(w.x) * gj;
        o.z = blo(w.y) * gj; o.w = bhi(w.y) * gj;
        out4[(size_t)(row0 + j) * (D / 4) + t] = o;
    }
}

extern "C" void kernel_launch(void* const* d_in, const int* in_sizes, int n_in,
                              void* d_out, int out_size, void* d_ws, size_t ws_size,
                              hipStream_t stream) {
    const float*         x      = (const float*)d_in[0];
    const float*         buf    = (const float*)d_in[1];
    const int*           mask_i = (const int*)d_in[2];
    const unsigned char* mask_b = (const unsigned char*)d_in[2];
    const float*         lt     = (const float*)d_in[3];
    const float*         lb     = (const float*)d_in[4];
    float*               out    = (float*)d_out;
    unsigned*            bfrag  = (unsigned*)d_ws;   // 64 KiB fragment image

    bfrag_kernel<<<32, 512, 0, stream>>>(buf, bfrag);
    gelu_gate_kernel<<<NBLK, TPB, 0, stream>>>(x, bfrag, mask_i, mask_b, lt, lb, out);
}